// Round 9
// baseline (3432.612 us; speedup 1.0000x reference)
//
#include <hip/hip_runtime.h>
#include <stdint.h>

// Spiking neural network:
//   B=32 batches, S=1024 steps, I=256 inputs, H=512 hidden, O=256 outputs.
// Phase 1: ic[B*S, H] (f64) = x[B*S, I] @ Win[I, H]   (feeds spike decisions)
// Phase 2: 8-way column-split scan; each block owns 64 neurons AND holds its
//          512x64 f32 slice of wlat in LDS (128KB) -> per-step gather never
//          touches L2. Mask exchange: dual-path write-once pair cells
//          (v, v^MAGIC): fast cells via plain/sc0 stores+loads (same-XCD L2,
//          ~200cyc) with an agent-scope LLC fallback cell polled every 8th
//          iteration -> correct regardless of XCD placement.
// Phase 3: out[B*S, O] (f32) = spikes @ Wout via bitmask-driven row sums.
//
// All decision-feeding arithmetic is f64 so spikes match an f64 numpy
// reference exactly; split/order nondeterminism only perturbs sums ~1e-15.

#define BB 32
#define SS 1024
#define II 256
#define HH 512
#define OO 256
#define NSPL 8
#define SLW 68                 // f32 words per LDS slice row (68*4=272B, 16B-aligned, odd/4 banks)
#define MAGICK 0x5A5A5A5A5A5A5A5AULL

// ---------------- Phase 1: f64-accumulate tiled GEMM ----------------
#define TM 64
#define TN 64
#define TK 16

__global__ __launch_bounds__(256) void ic_gemm_f64(const float* __restrict__ x,
                                                   const float* __restrict__ win,
                                                   double* __restrict__ ic) {
    __shared__ float As[TK][TM + 4];
    __shared__ float Bs[TK][TN];
    const int tid = threadIdx.x;
    const int m0 = blockIdx.x * TM;
    const int n0 = blockIdx.y * TN;
    const int tx = tid & 15;
    const int ty = tid >> 4;

    double acc[4][4];
#pragma unroll
    for (int i = 0; i < 4; ++i)
#pragma unroll
        for (int j = 0; j < 4; ++j) acc[i][j] = 0.0;

    const int lr = tid >> 2;
    const int lq = tid & 3;
    const int br = tid >> 4;
    const int bq = tid & 15;

    for (int k0 = 0; k0 < II; k0 += TK) {
        float4 av = *(const float4*)(x + (size_t)(m0 + lr) * II + k0 + lq * 4);
        float4 bv = *(const float4*)(win + (size_t)(k0 + br) * HH + n0 + bq * 4);
        As[lq * 4 + 0][lr] = av.x;
        As[lq * 4 + 1][lr] = av.y;
        As[lq * 4 + 2][lr] = av.z;
        As[lq * 4 + 3][lr] = av.w;
        *(float4*)(&Bs[br][bq * 4]) = bv;
        __syncthreads();
#pragma unroll
        for (int kk = 0; kk < TK; ++kk) {
            float4 a = *(const float4*)(&As[kk][ty * 4]);
            float4 b = *(const float4*)(&Bs[kk][tx * 4]);
            const double a0 = (double)a.x, a1 = (double)a.y, a2 = (double)a.z, a3 = (double)a.w;
            const double b0 = (double)b.x, b1 = (double)b.y, b2 = (double)b.z, b3 = (double)b.w;
            acc[0][0] += a0 * b0; acc[0][1] += a0 * b1; acc[0][2] += a0 * b2; acc[0][3] += a0 * b3;
            acc[1][0] += a1 * b0; acc[1][1] += a1 * b1; acc[1][2] += a1 * b2; acc[1][3] += a1 * b3;
            acc[2][0] += a2 * b0; acc[2][1] += a2 * b1; acc[2][2] += a2 * b2; acc[2][3] += a2 * b3;
            acc[3][0] += a3 * b0; acc[3][1] += a3 * b1; acc[3][2] += a3 * b2; acc[3][3] += a3 * b3;
        }
        __syncthreads();
    }

#pragma unroll
    for (int i = 0; i < 4; ++i) {
        double* row = ic + (size_t)(m0 + ty * 4 + i) * HH + n0 + tx * 4;
#pragma unroll
        for (int j = 0; j < 4; ++j) row[j] = acc[i][j];
    }
}

// ---------------- Phase 2: 8-way split scan, LDS-resident weights ----------------
// Grid: 256 blocks x 256 threads (1 block/CU, all co-resident).
// bid = j*32 + b: all 8 peers of batch b share bid%8 -> same XCD under the
// round-robin heuristic (fast path only; fallback keeps correctness).
__global__ __launch_bounds__(256) void snn_scan8v2(const double* __restrict__ ic,
                                                   const float* __restrict__ wlat,
                                                   const float* __restrict__ thr,
                                                   uint64_t* __restrict__ xf,
                                                   uint64_t* __restrict__ xa) {
    __shared__ float s_w[HH * SLW];      // 139,264 B: my 64-col slice, row stride 272B
    __shared__ int s_act[2][560];        // active-row byte offsets (r*272), 0-padded
    __shared__ int s_nact[2];
    __shared__ double s_part[16][68];    // per-chunk partials, swizzled slots
    __shared__ uint64_t s_m8[8];

    const int tid = threadIdx.x;
    const int bid = blockIdx.x;
    const int b = bid & 31;
    const int j = bid >> 5;
    const int ch = tid >> 4;             // gather chunk 0..15
    const int qd = tid & 15;             // column quad 0..15
    const int sw = (qd >> 2) & 3;

    const double* icb = ic + (size_t)b * SS * HH + (j << 6);
    uint64_t* xfb = xf + ((size_t)b * SS << 4);
    uint64_t* xab = xa + ((size_t)b * SS << 4);

    // ---- preload wlat slice into LDS (rows tid>>4 + 16k, quad qd) ----
    for (int r = tid >> 4; r < HH; r += 16) {
        const float4 v = *(const float4*)(wlat + (size_t)r * HH + (j << 6) + (qd << 2));
        *(float4*)&s_w[r * SLW + (qd << 2)] = v;
    }

    const bool owner = (tid < 64);
    double mp = 0.0, th = 0.0, icv = 0.0;
    int refrac = 0, rsw = 0;
    if (owner) {
        th = (double)thr[(j << 6) + tid];
        rsw = tid ^ ((tid >> 4) & 3);
        icv = icb[tid];                  // ic for t=0
    }
    if (tid == 0) { s_nact[0] = 0; s_nact[1] = 0; }
    for (int i = tid; i < 560; i += 256) { s_act[0][i] = 0; s_act[1][i] = 0; }
    __syncthreads();

    const char* wb = (const char*)s_w + (qd << 4);

    int cur = 0;
    for (int t = 0; t < SS; ++t) {
        const int nxt = cur ^ 1;

        // ---- gather phase: lateral partials from the LDS slice ----
        const int n = s_nact[cur];
        const int* act = s_act[cur];
        const int kcnt = (n > ch) ? ((n - ch + 15) >> 4) : 0;

        double ac0 = 0.0, ac1 = 0.0, ac2 = 0.0, ac3 = 0.0;
        {
            int idx = ch;
            int o0 = act[idx];           // 1-deep offset prefetch
            for (int k = 0; k < kcnt; ++k) {
                const int o1 = act[idx + 16];
                const float4 f = *(const float4*)(wb + o0);
                ac0 += (double)f.x;
                ac1 += (double)f.y;
                ac2 += (double)f.z;
                ac3 += (double)f.w;
                o0 = o1; idx += 16;
            }
        }
        {
            const int pb = qd << 2;
            s_part[ch][(pb + 0) ^ sw] = ac0;
            s_part[ch][(pb + 1) ^ sw] = ac1;
            s_part[ch][(pb + 2) ^ sw] = ac2;
            s_part[ch][(pb + 3) ^ sw] = ac3;
        }
        __syncthreads();  // B1: partials ready

        if (owner) {
            // ---- reduce + membrane update + ballot + dual publish ----
            double l0 = 0.0, l1 = 0.0, l2 = 0.0, l3 = 0.0;
#pragma unroll
            for (int c = 0; c < 16; c += 4) {
                l0 += s_part[c + 0][rsw];
                l1 += s_part[c + 1][rsw];
                l2 += s_part[c + 2][rsw];
                l3 += s_part[c + 3][rsw];
            }
            const double lat = (l0 + l1) + (l2 + l3);
            mp = 0.95 * mp + icv - lat;
            if (refrac > 0) mp = 0.0;
            refrac = (refrac > 0) ? (refrac - 1) : 0;
            const bool spike = (mp >= th);
            if (spike) { mp = 0.0; refrac = 2; }

            const uint64_t bm = __ballot(spike);
            if (tid == 0) {
                uint64_t* fc = xfb + ((size_t)t << 4) + (j << 1);
                uint64_t* ac_ = xab + ((size_t)t << 4) + (j << 1);
                const uint64_t bmx = bm ^ MAGICK;
                // fast cell: write-through L1 -> lands in this XCD's L2
                asm volatile("global_store_dwordx2 %0, %1, off sc0\n\t"
                             "global_store_dwordx2 %0, %2, off offset:8 sc0"
                             :: "v"(fc), "v"(bm), "v"(bmx) : "memory");
                // fallback cell: agent scope -> guaranteed visible at LLC
                __hip_atomic_store(ac_, bm, __ATOMIC_RELAXED,
                                   __HIP_MEMORY_SCOPE_AGENT);
                __hip_atomic_store(ac_ + 1, bmx, __ATOMIC_RELAXED,
                                   __HIP_MEMORY_SCOPE_AGENT);
                s_m8[j] = bm;
            }
            // prefetch next step's ic (hidden under poll + build)
            icv = icb[(size_t)(t < SS - 1 ? t + 1 : t) * HH + tid];

            // ---- poll 7 remote words: fast sc0 path + agent fallback ----
            if (tid < 16) {
                const int w = tid & 7;
                if (w != j) {
                    const uint64_t* fw = xfb + ((size_t)t << 4) + (w << 1) + (tid >> 3);
                    const uint64_t* aw = xab + ((size_t)t << 4) + (w << 1) + (tid >> 3);
                    uint64_t v = 0;
                    long guard = 0;
                    for (;;) {
                        uint64_t f;
                        asm volatile("global_load_dwordx2 %0, %1, off sc0\n\t"
                                     "s_waitcnt vmcnt(0)"
                                     : "=&v"(f) : "v"(fw) : "memory");
                        const uint64_t pf = __shfl(f, tid ^ 8, 64);
                        if ((f ^ pf) == MAGICK) { v = (tid < 8) ? f : pf; break; }
                        ++guard;
                        if ((guard & 7) == 0) {
                            const uint64_t a = __hip_atomic_load(
                                aw, __ATOMIC_RELAXED, __HIP_MEMORY_SCOPE_AGENT);
                            const uint64_t pa = __shfl(a, tid ^ 8, 64);
                            if ((a ^ pa) == MAGICK) { v = (tid < 8) ? a : pa; break; }
                        }
                        if (guard > (1L << 24)) break;  // loud fail, no hang
                    }
                    if (tid < 8) s_m8[w] = v;
                }
            }
        } else {
            // waves 1-3: re-pad next act buffer (last read ended at prev B1)
            for (int i = tid - 64; i < 560; i += 192) s_act[nxt][i] = 0;
        }
        __syncthreads();  // B2: s_m8 + padding ready

        // ---- build next active list (256 threads, 2 neurons each) ----
        {
            int rr = tid;
#pragma unroll
            for (int pass = 0; pass < 2; ++pass, rr += 256) {
                const int w = rr >> 6, bit = rr & 63;
                int base = 0, tot = 0;
                uint64_t myw = 0;
#pragma unroll
                for (int u = 0; u < 8; ++u) {
                    const uint64_t mw = s_m8[u];
                    const int pc = __popcll(mw);
                    if (u < w) base += pc;
                    if (u == w) myw = mw;
                    tot += pc;
                }
                if ((myw >> bit) & 1ull)
                    s_act[nxt][base + __popcll(myw & ((1ull << bit) - 1ull))] =
                        rr * (SLW * 4);  // LDS byte offset r*272
                if (tid == 0 && pass == 0) s_nact[nxt] = tot;
            }
        }
        __syncthreads();  // B3: next list ready
        cur = nxt;
    }
}

// ---------------- Phase 3: sparse output GEMM from fallback cells ----------------
__global__ __launch_bounds__(256) void out_gemm(const uint64_t* __restrict__ xa,
                                                const float* __restrict__ wout,
                                                float* __restrict__ out) {
    const int bt = blockIdx.x;
    const int o = threadIdx.x;
    __shared__ uint64_t sm[8];
    if (o < 8) sm[o] = xa[((size_t)bt << 4) + (o << 1)];
    __syncthreads();

    float acc = 0.0f;
#pragma unroll
    for (int w = 0; w < 8; ++w) {
        uint64_t bits = sm[w];
        while (bits) {
            const int h = (w << 6) + __ffsll((unsigned long long)bits) - 1;
            bits &= bits - 1;
            acc += wout[(size_t)h * OO + o];
        }
    }
    out[(size_t)bt * OO + o] = acc;
}

extern "C" void kernel_launch(void* const* d_in, const int* in_sizes, int n_in,
                              void* d_out, int out_size, void* d_ws, size_t ws_size,
                              hipStream_t stream) {
    const float* x    = (const float*)d_in[0];  // [B, S, I]
    const float* win  = (const float*)d_in[1];  // [I, H]
    const float* wlat = (const float*)d_in[2];  // [H, H]
    const float* wout = (const float*)d_in[3];  // [H, O]
    const float* thr  = (const float*)d_in[4];  // [H]
    float* out = (float*)d_out;                 // [B, S, O]

    // Workspace: ic f64 (128 MiB) | xa fallback cells (4 MiB) | xf fast cells (4 MiB)
    char* p = (char*)d_ws;
    double* ic = (double*)p;      p += (size_t)BB * SS * HH * sizeof(double);
    uint64_t* xa = (uint64_t*)p;  p += ((size_t)BB * SS << 4) * sizeof(uint64_t);
    uint64_t* xf = (uint64_t*)p;

    const int M = BB * SS;  // 32768
    ic_gemm_f64<<<dim3(M / TM, HH / TN), 256, 0, stream>>>(x, win, ic);
    snn_scan8v2<<<BB * NSPL, 256, 0, stream>>>(ic, wlat, thr, xf, xa);
    out_gemm<<<M, 256, 0, stream>>>(xa, wout, out);
}

// Round 11
// 2483.851 us; speedup vs baseline: 1.3820x; 1.3820x over previous
//
#include <hip/hip_runtime.h>
#include <stdint.h>

// Spiking neural network:
//   B=32 batches, S=1024 steps, I=256 inputs, H=512 hidden, O=256 outputs.
// Phase 1: ic[B*S, H] (f64) = x[B*S, I] @ Win[I, H]   (feeds spike decisions)
// Phase 2: 8-way column-split scan; 512x64 f32 wlat slice LDS-resident per
//          block. Mask exchange through HOT ring cells xh[b][t&7][w] (32KB,
//          LLC-resident) holding (bm, bm^hash(t)) — tag-validated, tearing-
//          and staleness-safe, paired 8B relaxed agent atomics.
// Phase 3: out[B*S, O] (f32) = spikes @ Wout via bitmask-driven row sums.
//
// All decision-feeding arithmetic is f64 so spikes match an f64 numpy
// reference exactly; split/order nondeterminism only perturbs sums ~1e-15.

#define BB 32
#define SS 1024
#define II 256
#define HH 512
#define OO 256
#define NSPL 8
#define SLW 68            // f32 words per LDS slice row (272B rows, 16B aligned)
#define ACTCAP 576        // 512 + 64-entry pad window
#define HKON 0x9E3779B97F4A7C15ULL

// ---------------- Phase 1: f64-accumulate tiled GEMM ----------------
#define TM 64
#define TN 64
#define TK 16

__global__ __launch_bounds__(256) void ic_gemm_f64(const float* __restrict__ x,
                                                   const float* __restrict__ win,
                                                   double* __restrict__ ic) {
    __shared__ float As[TK][TM + 4];
    __shared__ float Bs[TK][TN];
    const int tid = threadIdx.x;
    const int m0 = blockIdx.x * TM;
    const int n0 = blockIdx.y * TN;
    const int tx = tid & 15;
    const int ty = tid >> 4;

    double acc[4][4];
#pragma unroll
    for (int i = 0; i < 4; ++i)
#pragma unroll
        for (int j = 0; j < 4; ++j) acc[i][j] = 0.0;

    const int lr = tid >> 2;
    const int lq = tid & 3;
    const int br = tid >> 4;
    const int bq = tid & 15;

    for (int k0 = 0; k0 < II; k0 += TK) {
        float4 av = *(const float4*)(x + (size_t)(m0 + lr) * II + k0 + lq * 4);
        float4 bv = *(const float4*)(win + (size_t)(k0 + br) * HH + n0 + bq * 4);
        As[lq * 4 + 0][lr] = av.x;
        As[lq * 4 + 1][lr] = av.y;
        As[lq * 4 + 2][lr] = av.z;
        As[lq * 4 + 3][lr] = av.w;
        *(float4*)(&Bs[br][bq * 4]) = bv;
        __syncthreads();
#pragma unroll
        for (int kk = 0; kk < TK; ++kk) {
            float4 a = *(const float4*)(&As[kk][ty * 4]);
            float4 b = *(const float4*)(&Bs[kk][tx * 4]);
            const double a0 = (double)a.x, a1 = (double)a.y, a2 = (double)a.z, a3 = (double)a.w;
            const double b0 = (double)b.x, b1 = (double)b.y, b2 = (double)b.z, b3 = (double)b.w;
            acc[0][0] += a0 * b0; acc[0][1] += a0 * b1; acc[0][2] += a0 * b2; acc[0][3] += a0 * b3;
            acc[1][0] += a1 * b0; acc[1][1] += a1 * b1; acc[1][2] += a1 * b2; acc[1][3] += a1 * b3;
            acc[2][0] += a2 * b0; acc[2][1] += a2 * b1; acc[2][2] += a2 * b2; acc[2][3] += a2 * b3;
            acc[3][0] += a3 * b0; acc[3][1] += a3 * b1; acc[3][2] += a3 * b2; acc[3][3] += a3 * b3;
        }
        __syncthreads();
    }

#pragma unroll
    for (int i = 0; i < 4; ++i) {
        double* row = ic + (size_t)(m0 + ty * 4 + i) * HH + n0 + tx * 4;
#pragma unroll
        for (int j = 0; j < 4; ++j) row[j] = acc[i][j];
    }
}

// ---------------- Phase 2: 8-way split scan, hot-ring exchange ----------------
// Grid: 256 blocks x 512 threads. bid = j*32 + b; block owns columns/neurons
// [64j, 64j+64) and mask word j. Gather: 32 chunks (ch=tid>>4) x 16 quads
// (qd=tid&15); chunk ch processes active rows ch, ch+32, ...; intra-wave
// shfl_xor folds each wave's 4 chunks -> s_part[8][68]. Wave 0 then reduces,
// updates, publishes, polls, and builds the next active list in registers.
__global__ __launch_bounds__(512) void snn_scan8v3(const double* __restrict__ ic,
                                                   const float* __restrict__ wlat,
                                                   const float* __restrict__ thr,
                                                   uint64_t* __restrict__ hist,
                                                   uint64_t* __restrict__ xh) {
    __shared__ float s_w[HH * SLW];       // 139,264 B: my 64-col slice
    __shared__ int s_act[2][ACTCAP];      // row byte-offsets, pad-windowed
    __shared__ int s_nact[2];
    __shared__ double s_part[8][68];      // per-wave partials, swizzled slots

    const int tid = threadIdx.x;
    const int bid = blockIdx.x;
    const int b = bid & 31;
    const int j = bid >> 5;
    const int wv = tid >> 6;
    const int lane = tid & 63;
    const int ch = tid >> 4;              // 0..31
    const int qd = tid & 15;
    const int sw = (qd >> 2) & 3;

    const double* icb = ic + (size_t)b * SS * HH + (j << 6);
    uint64_t* hb = hist + ((size_t)b * SS << 3);
    uint64_t* xhb = xh + (b << 7);        // 8 slots x 8 words x 2 u64

    // ---- preload wlat slice (rows tid>>4 + 32k, quad qd) ----
    for (int r = tid >> 4; r < HH; r += 32) {
        const float4 v = *(const float4*)(wlat + (size_t)r * HH + (j << 6) + (qd << 2));
        *(float4*)&s_w[r * SLW + (qd << 2)] = v;
    }

    double mp = 0.0, th = 0.0, icv = 0.0;
    int refrac = 0, rsw = 0;
    if (wv == 0) {
        th = (double)thr[(j << 6) + lane];
        rsw = lane ^ ((lane >> 4) & 3);
        icv = icb[lane];                  // ic for t=0
    }
    if (tid == 0) { s_nact[0] = 0; s_nact[1] = 0; }
    for (int i = tid; i < ACTCAP; i += 512) { s_act[0][i] = 0; s_act[1][i] = 0; }
    __syncthreads();

    const char* wb = (const char*)s_w + (qd << 4);

    int cur = 0;
    for (int t = 0; t < SS; ++t) {
        const int nxt = cur ^ 1;

        // ---- gather: lateral partials from LDS slice ----
        const int n = s_nact[cur];
        const int* act = s_act[cur];
        const int kcnt = (n > ch) ? ((n - ch + 31) >> 5) : 0;

        double ac0 = 0.0, ac1 = 0.0, ac2 = 0.0, ac3 = 0.0;
        {
            int idx = ch;
            int o0 = act[idx];            // valid: ch < 32 always initialized
            for (int k = 0; k < kcnt; ++k) {
                const int o1 = act[idx + 32];   // pad-safe (< n+32 <= ACTCAP)
                const float4 f = *(const float4*)(wb + o0);
                ac0 += (double)f.x;
                ac1 += (double)f.y;
                ac2 += (double)f.z;
                ac3 += (double)f.w;
                o0 = o1; idx += 32;
            }
        }
        // fold the wave's 4 chunks: lanes ^16 (ch^1), ^32 (ch^2)
        ac0 += __shfl_xor(ac0, 16, 64); ac1 += __shfl_xor(ac1, 16, 64);
        ac2 += __shfl_xor(ac2, 16, 64); ac3 += __shfl_xor(ac3, 16, 64);
        ac0 += __shfl_xor(ac0, 32, 64); ac1 += __shfl_xor(ac1, 32, 64);
        ac2 += __shfl_xor(ac2, 32, 64); ac3 += __shfl_xor(ac3, 32, 64);
        if (lane < 16) {
            const int pb = qd << 2;
            s_part[wv][(pb + 0) ^ sw] = ac0;
            s_part[wv][(pb + 1) ^ sw] = ac1;
            s_part[wv][(pb + 2) ^ sw] = ac2;
            s_part[wv][(pb + 3) ^ sw] = ac3;
        }
        __syncthreads();  // B1: partials ready

        if (wv == 0) {
            // ---- reduce 8 partials + membrane update + spike ----
            const double lat = ((s_part[0][rsw] + s_part[1][rsw]) +
                                (s_part[2][rsw] + s_part[3][rsw])) +
                               ((s_part[4][rsw] + s_part[5][rsw]) +
                                (s_part[6][rsw] + s_part[7][rsw]));
            mp = 0.95 * mp + icv - lat;
            if (refrac > 0) mp = 0.0;
            refrac = (refrac > 0) ? (refrac - 1) : 0;
            const bool spike = (mp >= th);
            if (spike) { mp = 0.0; refrac = 2; }

            const uint64_t bm = __ballot(spike);
            const uint64_t h = (uint64_t)(t + 1) * HKON;
            uint64_t* ring = xhb + ((t & 7) << 4);

            if (lane == 0) {
                hb[((size_t)t << 3) + j] = bm;  // history for phase 3
                __hip_atomic_store(ring + (j << 1), bm,
                                   __ATOMIC_RELAXED, __HIP_MEMORY_SCOPE_AGENT);
                __hip_atomic_store(ring + (j << 1) + 1, bm ^ h,
                                   __ATOMIC_RELAXED, __HIP_MEMORY_SCOPE_AGENT);
            }

            // ---- poll 7 remote hot cells (paired 8B agent loads) ----
            uint64_t mword = bm;
            if (lane < 8 && lane != j) {
                const uint64_t* rc = ring + (lane << 1);
                long guard = 0;
                for (;;) {
                    const uint64_t v0 = __hip_atomic_load(
                        rc, __ATOMIC_RELAXED, __HIP_MEMORY_SCOPE_AGENT);
                    const uint64_t v1 = __hip_atomic_load(
                        rc + 1, __ATOMIC_RELAXED, __HIP_MEMORY_SCOPE_AGENT);
                    if ((v0 ^ v1) == h) { mword = v0; break; }  // tag fresh
                    if (++guard > (1L << 24)) break;  // loud fail, no hang
                }
            }

            // ---- broadcast words, build next act list in-register ----
            uint64_t m[8];
#pragma unroll
            for (int u = 0; u < 8; ++u) m[u] = __shfl(mword, u, 64);

            const int u = lane >> 3;
            const int bit0 = (lane << 3) & 63;
            int base = 0, tot = 0;
#pragma unroll
            for (int v = 0; v < 8; ++v) {
                const int pc = __popcll(m[v]);
                if (v < u) base += pc;
                tot += pc;
            }
            base += __popcll(m[u] & ((1ull << bit0) - 1ull));
            uint64_t bits = (m[u] >> bit0) & 0xFFull;
            const int row0 = lane << 3;
            while (bits) {
                const int o = __ffsll((unsigned long long)bits) - 1;
                s_act[nxt][base++] = (row0 + o) * (SLW * 4);
                bits &= bits - 1;
            }
            s_act[nxt][tot + lane] = 0;   // 64-entry pad window
            if (lane == 0) s_nact[nxt] = tot;

            // prefetch next step's ic LAST: its HBM latency hides under
            // B2 + next gather instead of serializing the poll loop.
            icv = icb[(size_t)(t < SS - 1 ? t + 1 : t) * HH + lane];
        }
        __syncthreads();  // B2: next list + count ready
        cur = nxt;
    }
}

// ---------------- Phase 3: sparse output GEMM from history ----------------
__global__ __launch_bounds__(256) void out_gemm(const uint64_t* __restrict__ hist,
                                                const float* __restrict__ wout,
                                                float* __restrict__ out) {
    const int bt = blockIdx.x;
    const int o = threadIdx.x;
    __shared__ uint64_t sm[8];
    if (o < 8) sm[o] = hist[((size_t)bt << 3) + o];
    __syncthreads();

    float acc = 0.0f;
#pragma unroll
    for (int w = 0; w < 8; ++w) {
        uint64_t bits = sm[w];
        while (bits) {
            const int h = (w << 6) + __ffsll((unsigned long long)bits) - 1;
            bits &= bits - 1;
            acc += wout[(size_t)h * OO + o];
        }
    }
    out[(size_t)bt * OO + o] = acc;
}

extern "C" void kernel_launch(void* const* d_in, const int* in_sizes, int n_in,
                              void* d_out, int out_size, void* d_ws, size_t ws_size,
                              hipStream_t stream) {
    const float* x    = (const float*)d_in[0];  // [B, S, I]
    const float* win  = (const float*)d_in[1];  // [I, H]
    const float* wlat = (const float*)d_in[2];  // [H, H]
    const float* wout = (const float*)d_in[3];  // [H, O]
    const float* thr  = (const float*)d_in[4];  // [H]
    float* out = (float*)d_out;                 // [B, S, O]

    // Workspace: ic f64 (128 MiB) | hist (2 MiB) | xh hot ring (32 KiB)
    char* p = (char*)d_ws;
    double* ic = (double*)p;       p += (size_t)BB * SS * HH * sizeof(double);
    uint64_t* hist = (uint64_t*)p; p += ((size_t)BB * SS << 3) * sizeof(uint64_t);
    uint64_t* xh = (uint64_t*)p;

    const int M = BB * SS;  // 32768
    ic_gemm_f64<<<dim3(M / TM, HH / TN), 256, 0, stream>>>(x, win, ic);
    snn_scan8v3<<<BB * NSPL, 512, 0, stream>>>(ic, wlat, thr, hist, xh);
    out_gemm<<<M, 256, 0, stream>>>(hist, wout, out);
}